// Round 3
// baseline (2367.071 us; speedup 1.0000x reference)
//
#include <hip/hip_runtime.h>
#include <hip/hip_bf16.h>
#include <math.h>

#define B_ 4
#define H_ 256
#define W_ 256
#define C_ 128
#define HEADS_ 4
#define HD_ 32
#define WS_ 8
#define SHIFT_ 4
#define T_ 64
#define NW_ 1024
#define M_ (B_*NW_*T_)   /* 262144 tokens */

__device__ __forceinline__ float b2f(unsigned short u){
    union { unsigned int i; float f; } c; c.i = ((unsigned int)u) << 16; return c.f;
}
__device__ __forceinline__ unsigned short f2b(float f){
    union { float f; unsigned int i; } c; c.f = f;
    unsigned int r = c.i + 0x7FFFu + ((c.i >> 16) & 1u);
    return (unsigned short)(r >> 16);
}
__device__ __forceinline__ void unpack8(uint4 wv, float* w){
    w[0]=b2f((unsigned short)(wv.x&0xffff)); w[1]=b2f((unsigned short)(wv.x>>16));
    w[2]=b2f((unsigned short)(wv.y&0xffff)); w[3]=b2f((unsigned short)(wv.y>>16));
    w[4]=b2f((unsigned short)(wv.z&0xffff)); w[5]=b2f((unsigned short)(wv.z>>16));
    w[6]=b2f((unsigned short)(wv.w&0xffff)); w[7]=b2f((unsigned short)(wv.w>>16));
}
__device__ __forceinline__ int region_id(int x){ return (x < 248) ? 0 : ((x < 252) ? 1 : 2); }

// stage a 32x128 fp32 weight chunk into bf16 LDS
__device__ __forceinline__ void stage_w_chunk(const float* __restrict__ Wg,
        unsigned short Wbuf[32][C_], int tid)
{
    const float4* src = (const float4*)Wg;
    for (int i = tid; i < 1024; i += 256) {
        float4 v = src[i];
        ushort4 o; o.x=f2b(v.x); o.y=f2b(v.y); o.z=f2b(v.z); o.w=f2b(v.w);
        *(ushort4*)((unsigned short*)Wbuf + i*4) = o;
    }
}

// 64x128 tile GEMM: acc[4][8] += Xs(64x128 bf16, stride 130) @ Wg(128x128 fp32 global).
// Weights streamed through a 32-row bf16 LDS chunk buffer (4 chunks).
__device__ __forceinline__ void gemm64(const unsigned short Xs[T_][130],
        unsigned short Wbuf[32][C_], const float* __restrict__ Wg,
        int tid, float acc[4][8])
{
    int cx = tid & 15, ry = tid >> 4;
    for (int c = 0; c < 4; c++) {
        __syncthreads();   // prev consumers of Wbuf done
        stage_w_chunk(Wg + c*32*C_, Wbuf, tid);
        __syncthreads();
        for (int k = 0; k < 32; k++) {
            float a[4];
            #pragma unroll
            for (int i = 0; i < 4; i++) a[i] = b2f(Xs[ry*4+i][c*32+k]);
            float w[8]; unpack8(*(const uint4*)&Wbuf[k][cx*8], w);
            #pragma unroll
            for (int i = 0; i < 4; i++)
                #pragma unroll
                for (int j = 0; j < 8; j++) acc[i][j] += a[i] * w[j];
        }
    }
}

// K1: LN1 + shift-gather + QKV + windowed attention + proj + unshift-scatter
// + residual. One block per window; zero HBM workspace; xres -> d_out (fp32).
__global__ __launch_bounds__(256) void swin_attn_kernel(
        const float* __restrict__ hidden,
        const float* __restrict__ ln1_s, const float* __restrict__ ln1_b,
        const float* __restrict__ q_w, const float* __restrict__ q_b,
        const float* __restrict__ k_w, const float* __restrict__ k_b,
        const float* __restrict__ v_w, const float* __restrict__ v_b,
        const float* __restrict__ p_w, const float* __restrict__ p_b,
        const float* __restrict__ rpb,
        float* __restrict__ xres)
{
    __shared__ unsigned short Xs[T_][130];    // LN1 out, later attn-out (padded stride)
    __shared__ unsigned short Wbuf[32][C_];   // weight chunk (bf16)
    __shared__ unsigned short Ks[T_][C_];     // k tile, col = head*32+d
    __shared__ unsigned short Vs[T_][C_];
    __shared__ float rpbs[225*HEADS_];

    int tid = threadIdx.x;
    int wv = tid >> 6, lane = tid & 63;       // wv doubles as head id
    int gw = blockIdx.x;
    int wi = gw & (NW_-1), b = gw >> 10;
    int hb = wi >> 5, wb = wi & 31;

    for (int idx = tid; idx < 225*HEADS_; idx += 256) rpbs[idx] = rpb[idx];

    // ---- LN1 over gathered (rolled) tokens; wave wv handles 16 tokens ----
    for (int it = 0; it < 16; it++) {
        int t = wv*16 + it;
        int th = t >> 3, tw = t & 7;
        int h = (hb*8 + th + SHIFT_) & 255;   // roll(-S): dest[i] = x[(i+S)%H]
        int w = (wb*8 + tw + SHIFT_) & 255;
        size_t src = ((size_t)((b<<16) + (h<<8) + w)) * C_;
        float2 u = *(const float2*)(hidden + src + 2*lane);
        float x0 = u.x, x1 = u.y;
        float s = x0 + x1, ss = x0*x0 + x1*x1;
        #pragma unroll
        for (int m = 32; m > 0; m >>= 1) {
            s  += __shfl_xor(s,  m, 64);
            ss += __shfl_xor(ss, m, 64);
        }
        float mean = s * (1.0f/C_);
        float var  = ss * (1.0f/C_) - mean*mean;
        float rstd = rsqrtf(var + 1e-5f);
        int c0 = 2*lane;
        float y0 = (x0 - mean) * rstd * ln1_s[c0]   + ln1_b[c0];
        float y1 = (x1 - mean) * rstd * ln1_s[c0+1] + ln1_b[c0+1];
        ushort2 o; o.x = f2b(y0); o.y = f2b(y1);
        *(ushort2*)&Xs[t][c0] = o;
    }

    // ---- Q GEMM, attention-matched mapping: thread owns row=lane, cols wv*32..+31
    float qreg[32];
    {
        float qacc[32] = {};
        for (int c = 0; c < 4; c++) {
            __syncthreads();   // (c=0: also covers LN1 Xs writes)
            stage_w_chunk(q_w + c*32*C_, Wbuf, tid);
            __syncthreads();
            for (int k = 0; k < 32; k++) {
                float a = b2f(Xs[lane][c*32 + k]);
                const uint4* wr = (const uint4*)&Wbuf[k][wv*32];
                #pragma unroll
                for (int q8 = 0; q8 < 4; q8++) {
                    float w8[8]; unpack8(wr[q8], w8);
                    #pragma unroll
                    for (int j = 0; j < 8; j++) qacc[q8*8+j] += a * w8[j];
                }
            }
        }
        #pragma unroll
        for (int j = 0; j < 32; j++)
            qreg[j] = (qacc[j] + q_b[wv*32 + j]) * 0.17677669529663687f;
    }

    // ---- K and V GEMMs (standard 4x8 mapping) ----
    {
        int cx = tid & 15, ry = tid >> 4;
        float acc[4][8] = {};
        gemm64(Xs, Wbuf, k_w, tid, acc);
        #pragma unroll
        for (int i = 0; i < 4; i++)
            #pragma unroll
            for (int j = 0; j < 8; j++)
                Ks[ry*4+i][cx*8+j] = f2b(acc[i][j] + k_b[cx*8+j]);
        float acc2[4][8] = {};
        gemm64(Xs, Wbuf, v_w, tid, acc2);
        #pragma unroll
        for (int i = 0; i < 4; i++)
            #pragma unroll
            for (int j = 0; j < 8; j++)
                Vs[ry*4+i][cx*8+j] = f2b(acc2[i][j] + v_b[cx*8+j]);
    }
    __syncthreads();   // K/V tiles ready

    // ---- attention: head = wv, query row = lane ----
    {
        int th = lane >> 3, tw = lane & 7;
        int cid_i = region_id(hb*8 + th)*3 + region_id(wb*8 + tw);
        float s[T_];
        float mmax = -1e30f;
        #pragma unroll
        for (int j = 0; j < T_; j++) {
            const unsigned int* krow = (const unsigned int*)&Ks[j][wv*32];
            float d = 0.f;
            #pragma unroll
            for (int t2 = 0; t2 < 16; t2++) {
                unsigned int u = krow[t2];
                d += qreg[2*t2]   * b2f((unsigned short)(u & 0xffff));
                d += qreg[2*t2+1] * b2f((unsigned short)(u >> 16));
            }
            int jh = j >> 3, jw = j & 7;
            d += rpbs[((th - jh + 7)*15 + (tw - jw + 7))*HEADS_ + wv];
            int cid_j = region_id(hb*8 + jh)*3 + region_id(wb*8 + jw);
            if (cid_i != cid_j) d -= 100.f;
            s[j] = d;
            mmax = fmaxf(mmax, d);
        }
        float sum = 0.f;
        #pragma unroll
        for (int j = 0; j < T_; j++) { float p = __expf(s[j] - mmax); s[j] = p; sum += p; }
        float inv = 1.0f / sum;
        float o[32] = {};
        #pragma unroll
        for (int j = 0; j < T_; j++) {
            float p = s[j];
            const unsigned int* vrow = (const unsigned int*)&Vs[j][wv*32];
            #pragma unroll
            for (int t2 = 0; t2 < 16; t2++) {
                unsigned int u = vrow[t2];
                o[2*t2]   += p * b2f((unsigned short)(u & 0xffff));
                o[2*t2+1] += p * b2f((unsigned short)(u >> 16));
            }
        }
        // write attn-out into Xs (Xs dead after V gemm; next read after a sync)
        #pragma unroll
        for (int t2 = 0; t2 < 32; t2++) Xs[lane][wv*32 + t2] = f2b(o[t2] * inv);
    }

    // ---- proj GEMM + unshift scatter + residual -> xres (d_out, fp32) ----
    {
        int cx = tid & 15, ry = tid >> 4;
        float acc[4][8] = {};
        gemm64(Xs, Wbuf, p_w, tid, acc);   // chunk0's syncs order Xs writes
        #pragma unroll
        for (int i = 0; i < 4; i++) {
            int t = ry*4 + i;
            int th = t >> 3, tw = t & 7;
            int h = (hb*8 + th + SHIFT_) & 255;   // window-reverse + roll(+S)
            int w = (wb*8 + tw + SHIFT_) & 255;
            size_t dst = ((size_t)((b<<16) + (h<<8) + w)) * C_;
            #pragma unroll
            for (int j = 0; j < 8; j++) {
                int c = cx*8 + j;
                xres[dst + c] = hidden[dst + c] + acc[i][j] + p_b[c];
            }
        }
    }
}

// K2: LN2 + MLP, in-place on d_out (each block owns rows row0..row0+63).
// out[r] = xres[r] + gelu(ln2(xres[r]) @ fc1 + b1) @ fc2 + b2
__global__ __launch_bounds__(256) void mlp_ln_kernel(
        float* __restrict__ xio,
        const float* __restrict__ ln2_s, const float* __restrict__ ln2_b,
        const float* __restrict__ W1, const float* __restrict__ b1,
        const float* __restrict__ W2, const float* __restrict__ b2)
{
    __shared__ unsigned short As[T_][130];
    __shared__ unsigned short G[T_][66];
    __shared__ unsigned short W1s[C_][T_];
    __shared__ unsigned short W2s[T_][C_];
    int tid = threadIdx.x, wv = tid >> 6, lane = tid & 63;
    size_t row0 = (size_t)blockIdx.x * 64;

    // ---- LN2 (block-local rows) ----
    for (int it = 0; it < 16; it++) {
        int t = wv*16 + it;
        const float* xp = xio + (row0 + t)*C_;
        float2 u = *(const float2*)(xp + 2*lane);
        float x0 = u.x, x1 = u.y;
        float s = x0 + x1, ss = x0*x0 + x1*x1;
        #pragma unroll
        for (int m = 32; m > 0; m >>= 1) {
            s  += __shfl_xor(s,  m, 64);
            ss += __shfl_xor(ss, m, 64);
        }
        float mean = s * (1.0f/C_);
        float var  = ss * (1.0f/C_) - mean*mean;
        float rstd = rsqrtf(var + 1e-5f);
        int c0 = 2*lane;
        float y0 = (x0 - mean) * rstd * ln2_s[c0]   + ln2_b[c0];
        float y1 = (x1 - mean) * rstd * ln2_s[c0+1] + ln2_b[c0+1];
        ushort2 o; o.x = f2b(y0); o.y = f2b(y1);
        *(ushort2*)&As[t][c0] = o;
    }

    int cx  = tid & 15, ry  = tid >> 4;   // stage2: 4 rows x 8 cols of 64x128
    int cx1 = tid & 7,  ry1 = tid >> 3;   // stage1: 2 rows x 8 cols of 64x64
    float acc2[4][8] = {};
    for (int ch = 0; ch < 8; ch++) {
        __syncthreads();   // (ch=0: also covers As writes)
        // W1 chunk: 128 rows x 64 cols (row stride 512) -> W1s bf16
        for (int idx = tid; idx < 2048; idx += 256) {
            int ks = idx >> 4, cs4 = (idx & 15) * 4;
            float4 v = *(const float4*)(W1 + ks*512 + ch*64 + cs4);
            ushort4 o; o.x=f2b(v.x); o.y=f2b(v.y); o.z=f2b(v.z); o.w=f2b(v.w);
            *(ushort4*)&W1s[ks][cs4] = o;
        }
        // W2 chunk: 64 rows x 128 cols, contiguous -> W2s bf16
        {
            const float4* src2 = (const float4*)(W2 + (size_t)ch*64*C_);
            for (int i = tid; i < 2048; i += 256) {
                float4 v = src2[i];
                ushort4 o; o.x=f2b(v.x); o.y=f2b(v.y); o.z=f2b(v.z); o.w=f2b(v.w);
                *(ushort4*)((unsigned short*)W2s + i*4) = o;
            }
        }
        __syncthreads();
        float a1[2][8] = {};
        for (int k2 = 0; k2 < 128; k2++) {
            float a[2];
            a[0] = b2f(As[ry1*2+0][k2]);
            a[1] = b2f(As[ry1*2+1][k2]);
            float w[8]; unpack8(*(const uint4*)&W1s[k2][cx1*8], w);
            #pragma unroll
            for (int i = 0; i < 2; i++)
                #pragma unroll
                for (int j = 0; j < 8; j++) a1[i][j] += a[i] * w[j];
        }
        #pragma unroll
        for (int i = 0; i < 2; i++)
            #pragma unroll
            for (int j = 0; j < 8; j++) {
                int c = ch*64 + cx1*8 + j;
                float h = a1[i][j] + b1[c];
                float g = 0.5f * h * (1.0f + erff(h * 0.70710678118654752f));
                G[ry1*2+i][cx1*8+j] = f2b(g);
            }
        __syncthreads();
        for (int k2 = 0; k2 < 64; k2++) {
            float a[4];
            #pragma unroll
            for (int i = 0; i < 4; i++) a[i] = b2f(G[ry*4+i][k2]);
            float w[8]; unpack8(*(const uint4*)&W2s[k2][cx*8], w);
            #pragma unroll
            for (int i = 0; i < 4; i++)
                #pragma unroll
                for (int j = 0; j < 8; j++) acc2[i][j] += a[i] * w[j];
        }
    }
    // ---- epilogue: residual (same-thread read-then-write, in-place safe) ----
    #pragma unroll
    for (int i = 0; i < 4; i++) {
        size_t r = row0 + ry*4 + i;
        #pragma unroll
        for (int j = 0; j < 8; j++) {
            int c = cx*8 + j;
            float xv = xio[r*C_ + c];
            xio[r*C_ + c] = xv + acc2[i][j] + b2[c];
        }
    }
}

extern "C" void kernel_launch(void* const* d_in, const int* in_sizes, int n_in,
                              void* d_out, int out_size, void* d_ws, size_t ws_size,
                              hipStream_t stream) {
    (void)in_sizes; (void)n_in; (void)out_size; (void)d_ws; (void)ws_size;
    const float* hidden = (const float*)d_in[0];
    const float* ln1_s  = (const float*)d_in[1];
    const float* ln1_b  = (const float*)d_in[2];
    const float* q_w    = (const float*)d_in[3];
    const float* q_b    = (const float*)d_in[4];
    const float* k_w    = (const float*)d_in[5];
    const float* k_b    = (const float*)d_in[6];
    const float* v_w    = (const float*)d_in[7];
    const float* v_b    = (const float*)d_in[8];
    const float* p_w    = (const float*)d_in[9];
    const float* p_b    = (const float*)d_in[10];
    const float* rpb    = (const float*)d_in[11];
    const float* ln2_s  = (const float*)d_in[12];
    const float* ln2_b  = (const float*)d_in[13];
    const float* fc1_w  = (const float*)d_in[14];
    const float* fc1_b  = (const float*)d_in[15];
    const float* fc2_w  = (const float*)d_in[16];
    const float* fc2_b  = (const float*)d_in[17];
    float* outp = (float*)d_out;

    // K1 writes xres into d_out; K2 transforms it in-place to the final output.
    swin_attn_kernel<<<B_*NW_, 256, 0, stream>>>(hidden, ln1_s, ln1_b,
            q_w, q_b, k_w, k_b, v_w, v_b, p_w, p_b, rpb, outp);
    mlp_ln_kernel<<<M_/64, 256, 0, stream>>>(outp, ln2_s, ln2_b,
            fc1_w, fc1_b, fc2_w, fc2_b);
}

// Round 4
// 698.827 us; speedup vs baseline: 3.3872x; 3.3872x over previous
//
#include <hip/hip_runtime.h>
#include <hip/hip_bf16.h>
#include <math.h>

#define B_ 4
#define H_ 256
#define W_ 256
#define C_ 128
#define HEADS_ 4
#define HD_ 32
#define WS_ 8
#define SHIFT_ 4
#define T_ 64
#define NW_ 1024
#define M_ (B_*NW_*T_)   /* 262144 tokens */

typedef float floatx4 __attribute__((ext_vector_type(4)));
typedef short bf16x8 __attribute__((ext_vector_type(8)));   // 8 bf16 in 4 VGPRs
typedef unsigned short ushort8v __attribute__((ext_vector_type(8)));

#define MFMA16(a,b,c) __builtin_amdgcn_mfma_f32_16x16x32_bf16(a,b,c,0,0,0)

__device__ __forceinline__ float b2f(unsigned short u){
    union { unsigned int i; float f; } c; c.i = ((unsigned int)u) << 16; return c.f;
}
__device__ __forceinline__ unsigned short f2b(float f){
    union { float f; unsigned int i; } c; c.f = f;
    unsigned int r = c.i + 0x7FFFu + ((c.i >> 16) & 1u);
    return (unsigned short)(r >> 16);
}
__device__ __forceinline__ int region_id(int x){ return (x < 248) ? 0 : ((x < 252) ? 1 : 2); }

__device__ __forceinline__ bf16x8 ldfrag(const unsigned short* p){
    return *(const bf16x8*)p;                       // ds_read_b128 (16B-aligned rows)
}
__device__ __forceinline__ bf16x8 ldfrag_strided(const unsigned short* p, int stride){
    ushort8v u;
    #pragma unroll
    for (int j = 0; j < 8; j++) u[j] = p[j*stride];
    return __builtin_bit_cast(bf16x8, u);
}
__device__ __forceinline__ floatx4 fzero(){ floatx4 v = {0.f,0.f,0.f,0.f}; return v; }

// C[64x128] = Xs[64x128] @ Wg[128x128]; wave wv owns n-cols [32wv,32wv+32).
// acc[m][u]: D rows 16m+4*quad+r, col 32wv+16u+(lane&15). Wc = k-major chunk buf.
__device__ __forceinline__ void gemm64x128(
        const unsigned short (*Xs)[136], unsigned short (*Wc)[132],
        const float* __restrict__ Wg, int tid, int wv, int quad, int l15,
        floatx4 acc[4][2])
{
    for (int c = 0; c < 4; c++) {
        __syncthreads();                       // prev Wc consumers done
        #pragma unroll
        for (int it = 0; it < 4; it++) {
            int idx = tid + it*256;            // 1024 float4 groups = 32x128
            int kk = idx >> 5;
            int n4 = (idx & 31) * 4;
            float4 v = *(const float4*)(Wg + (size_t)(c*32 + kk)*C_ + n4);
            ushort4 o; o.x=f2b(v.x); o.y=f2b(v.y); o.z=f2b(v.z); o.w=f2b(v.w);
            *(ushort4*)&Wc[kk][n4] = o;
        }
        __syncthreads();
        bf16x8 bf0 = ldfrag_strided(&Wc[quad*8][32*wv + l15],      132);
        bf16x8 bf1 = ldfrag_strided(&Wc[quad*8][32*wv + 16 + l15], 132);
        #pragma unroll
        for (int m = 0; m < 4; m++) {
            bf16x8 af = ldfrag(&Xs[16*m + l15][c*32 + quad*8]);
            acc[m][0] = MFMA16(af, bf0, acc[m][0]);
            acc[m][1] = MFMA16(af, bf1, acc[m][1]);
        }
    }
}

// K1: LN1 + shift-gather + QKV + windowed attention + proj + unshift-scatter
// + residual. One block per window; zero HBM workspace; xres -> d_out (fp32).
__global__ __launch_bounds__(256) void swin_attn_kernel(
        const float* __restrict__ hidden,
        const float* __restrict__ ln1_s, const float* __restrict__ ln1_b,
        const float* __restrict__ q_w, const float* __restrict__ q_b,
        const float* __restrict__ k_w, const float* __restrict__ k_b,
        const float* __restrict__ v_w, const float* __restrict__ v_b,
        const float* __restrict__ p_w, const float* __restrict__ p_b,
        const float* __restrict__ rpb,
        float* __restrict__ xres)
{
    __shared__ unsigned short Xs[T_][136];   // LN1-out -> Q -> attn-out
    __shared__ unsigned short Ks[T_][136];   // K tile; later P (heads 0,1)
    __shared__ unsigned short Vs[T_][134];   // V tile (strided B-operand)
    __shared__ __align__(16) unsigned char U[10240]; // Wc | rpb f32 | P (heads 2,3)

    unsigned short (*Wc)[132] = (unsigned short(*)[132])U;
    float* rpbf = (float*)U;

    int tid = threadIdx.x;
    int wv = tid >> 6, lane = tid & 63;      // wv doubles as head id
    int quad = lane >> 4, l15 = lane & 15;
    int gw = blockIdx.x;
    int wi = gw & (NW_-1), b = gw >> 10;
    int hb = wi >> 5, wb = wi & 31;

    // ---- LN1 over gathered (rolled) tokens; wave wv handles 16 tokens ----
    for (int it = 0; it < 16; it++) {
        int t = wv*16 + it;
        int th = t >> 3, tw = t & 7;
        int h = (hb*8 + th + SHIFT_) & 255;
        int w = (wb*8 + tw + SHIFT_) & 255;
        size_t src = ((size_t)((b<<16) + (h<<8) + w)) * C_;
        float2 u = *(const float2*)(hidden + src + 2*lane);
        float x0 = u.x, x1 = u.y;
        float s = x0 + x1, ss = x0*x0 + x1*x1;
        #pragma unroll
        for (int m = 32; m > 0; m >>= 1) {
            s  += __shfl_xor(s,  m, 64);
            ss += __shfl_xor(ss, m, 64);
        }
        float mean = s * (1.0f/C_);
        float var  = ss * (1.0f/C_) - mean*mean;
        float rstd = rsqrtf(var + 1e-5f);
        int c0 = 2*lane;
        ushort2 o;
        o.x = f2b((x0 - mean) * rstd * ln1_s[c0]   + ln1_b[c0]);
        o.y = f2b((x1 - mean) * rstd * ln1_s[c0+1] + ln1_b[c0+1]);
        *(ushort2*)&Xs[t][c0] = o;
    }

    // ---- K GEMM -> Ks ----
    {
        floatx4 acc[4][2];
        #pragma unroll
        for (int m = 0; m < 4; m++) { acc[m][0] = fzero(); acc[m][1] = fzero(); }
        gemm64x128(Xs, Wc, k_w, tid, wv, quad, l15, acc);
        float kb0 = k_b[32*wv + l15], kb1 = k_b[32*wv + 16 + l15];
        #pragma unroll
        for (int m = 0; m < 4; m++)
            #pragma unroll
            for (int r = 0; r < 4; r++) {
                int q = 16*m + 4*quad + r;
                Ks[q][32*wv + l15]      = f2b(acc[m][0][r] + kb0);
                Ks[q][32*wv + 16 + l15] = f2b(acc[m][1][r] + kb1);
            }
    }
    // ---- V GEMM -> Vs ----
    {
        floatx4 acc[4][2];
        #pragma unroll
        for (int m = 0; m < 4; m++) { acc[m][0] = fzero(); acc[m][1] = fzero(); }
        gemm64x128(Xs, Wc, v_w, tid, wv, quad, l15, acc);
        float vb0 = v_b[32*wv + l15], vb1 = v_b[32*wv + 16 + l15];
        #pragma unroll
        for (int m = 0; m < 4; m++)
            #pragma unroll
            for (int r = 0; r < 4; r++) {
                int q = 16*m + 4*quad + r;
                Vs[q][32*wv + l15]      = f2b(acc[m][0][r] + vb0);
                Vs[q][32*wv + 16 + l15] = f2b(acc[m][1][r] + vb1);
            }
    }
    // ---- Q GEMM -> regs ----
    floatx4 qacc[4][2];
    #pragma unroll
    for (int m = 0; m < 4; m++) { qacc[m][0] = fzero(); qacc[m][1] = fzero(); }
    gemm64x128(Xs, Wc, q_w, tid, wv, quad, l15, qacc);
    __syncthreads();                          // all Xs/Wc reads done
    // stage rpb table (into U; Wc dead) + write Q into Xs (D-layout -> A-rows)
    for (int i = tid; i < 225*HEADS_; i += 256) rpbf[i] = rpb[i];
    {
        const float sc = 0.17677669529663687f;
        float qb0 = q_b[32*wv + l15], qb1 = q_b[32*wv + 16 + l15];
        #pragma unroll
        for (int m = 0; m < 4; m++)
            #pragma unroll
            for (int r = 0; r < 4; r++) {
                int q = 16*m + 4*quad + r;
                Xs[q][32*wv + l15]      = f2b((qacc[m][0][r] + qb0) * sc);
                Xs[q][32*wv + 16 + l15] = f2b((qacc[m][1][r] + qb1) * sc);
            }
    }
    __syncthreads();

    // ---- S = Q K^T (wave = head), 16 MFMAs, K=32 = head dim ----
    floatx4 sacc[4][4];
    #pragma unroll
    for (int m = 0; m < 4; m++)
        #pragma unroll
        for (int n = 0; n < 4; n++) sacc[m][n] = fzero();
    {
        bf16x8 qf[4], kf[4];
        #pragma unroll
        for (int m = 0; m < 4; m++) qf[m] = ldfrag(&Xs[16*m + l15][32*wv + quad*8]);
        #pragma unroll
        for (int n = 0; n < 4; n++) kf[n] = ldfrag(&Ks[16*n + l15][32*wv + quad*8]);
        #pragma unroll
        for (int m = 0; m < 4; m++)
            #pragma unroll
            for (int n = 0; n < 4; n++) sacc[m][n] = MFMA16(qf[m], kf[n], sacc[m][n]);
    }
    // ---- bias + shift-mask + softmax (rows spread over 16-lane groups) ----
    {
        int jh_[4], jw_[4], cidj_[4];
        #pragma unroll
        for (int n = 0; n < 4; n++) {
            int kt = 16*n + l15;
            jh_[n] = kt >> 3; jw_[n] = kt & 7;
            cidj_[n] = region_id(hb*8 + jh_[n])*3 + region_id(wb*8 + jw_[n]);
        }
        #pragma unroll
        for (int m = 0; m < 4; m++)
            #pragma unroll
            for (int r = 0; r < 4; r++) {
                int q = 16*m + 4*quad + r;
                int th = q >> 3, twq = q & 7;
                int cidi = region_id(hb*8 + th)*3 + region_id(wb*8 + twq);
                float v[4];
                #pragma unroll
                for (int n = 0; n < 4; n++) {
                    float d = sacc[m][n][r];
                    d += rpbf[((th - jh_[n] + 7)*15 + (twq - jw_[n] + 7))*HEADS_ + wv];
                    if (cidi != cidj_[n]) d -= 100.f;
                    v[n] = d;
                }
                float mx = fmaxf(fmaxf(v[0],v[1]), fmaxf(v[2],v[3]));
                #pragma unroll
                for (int off = 1; off < 16; off <<= 1) mx = fmaxf(mx, __shfl_xor(mx, off, 64));
                float sum = 0.f;
                #pragma unroll
                for (int n = 0; n < 4; n++) { v[n] = __expf(v[n] - mx); sum += v[n]; }
                #pragma unroll
                for (int off = 1; off < 16; off <<= 1) sum += __shfl_xor(sum, off, 64);
                float inv = 1.0f / sum;
                #pragma unroll
                for (int n = 0; n < 4; n++) sacc[m][n][r] = v[n] * inv;
            }
    }
    __syncthreads();                          // Ks + rpbf dead

    // ---- PV: P staged per 32-kt block into dead Ks/U regions ----
    unsigned short* Ph = (wv < 2) ? (&Ks[0][0] + wv*2560)
                                  : ((unsigned short*)U + (wv-2)*2560);
    floatx4 oacc[4][2];
    #pragma unroll
    for (int m = 0; m < 4; m++) { oacc[m][0] = fzero(); oacc[m][1] = fzero(); }
    for (int kb = 0; kb < 2; kb++) {
        #pragma unroll
        for (int m = 0; m < 4; m++)
            #pragma unroll
            for (int r = 0; r < 4; r++) {
                int q = 16*m + 4*quad + r;
                Ph[q*40 + l15]      = f2b(sacc[m][2*kb+0][r]);
                Ph[q*40 + 16 + l15] = f2b(sacc[m][2*kb+1][r]);
            }
        __syncthreads();
        bf16x8 bf0 = ldfrag_strided(&Vs[kb*32 + quad*8][32*wv + l15],      134);
        bf16x8 bf1 = ldfrag_strided(&Vs[kb*32 + quad*8][32*wv + 16 + l15], 134);
        #pragma unroll
        for (int m = 0; m < 4; m++) {
            bf16x8 af = ldfrag(&Ph[(16*m + l15)*40 + quad*8]);
            oacc[m][0] = MFMA16(af, bf0, oacc[m][0]);
            oacc[m][1] = MFMA16(af, bf1, oacc[m][1]);
        }
        __syncthreads();
    }
    // ---- attn-out -> Xs (wave-private cols) ----
    #pragma unroll
    for (int m = 0; m < 4; m++)
        #pragma unroll
        for (int r = 0; r < 4; r++) {
            int q = 16*m + 4*quad + r;
            Xs[q][32*wv + l15]      = f2b(oacc[m][0][r]);
            Xs[q][32*wv + 16 + l15] = f2b(oacc[m][1][r]);
        }
    // ---- proj GEMM + unshift scatter + residual -> xres ----
    {
        floatx4 acc[4][2];
        #pragma unroll
        for (int m = 0; m < 4; m++) { acc[m][0] = fzero(); acc[m][1] = fzero(); }
        gemm64x128(Xs, Wc, p_w, tid, wv, quad, l15, acc);  // chunk-0 barrier orders O-writes
        float pb0 = p_b[32*wv + l15], pb1 = p_b[32*wv + 16 + l15];
        #pragma unroll
        for (int m = 0; m < 4; m++)
            #pragma unroll
            for (int r = 0; r < 4; r++) {
                int t = 16*m + 4*quad + r;
                int th = t >> 3, tw = t & 7;
                int h = (hb*8 + th + SHIFT_) & 255;
                int w = (wb*8 + tw + SHIFT_) & 255;
                size_t dst = ((size_t)((b<<16) + (h<<8) + w)) * C_;
                int c0 = 32*wv + l15;
                xres[dst + c0]      = hidden[dst + c0]      + acc[m][0][r] + pb0;
                xres[dst + c0 + 16] = hidden[dst + c0 + 16] + acc[m][1][r] + pb1;
            }
    }
}

// K2: LN2 + MLP in-place on d_out. Hidden dim looped in 8 chunks of 64.
__global__ __launch_bounds__(256) void mlp_ln_kernel(
        float* __restrict__ xio,
        const float* __restrict__ ln2_s, const float* __restrict__ ln2_b,
        const float* __restrict__ W1, const float* __restrict__ b1,
        const float* __restrict__ W2, const float* __restrict__ b2)
{
    __shared__ unsigned short As[T_][136];    // LN2 out (A-operand)
    __shared__ unsigned short G[T_][72];      // gelu out (A-operand stage2)
    __shared__ unsigned short W1c[C_][68];    // k-major W1 chunk
    __shared__ unsigned short W2c[T_][132];   // k-major W2 chunk
    int tid = threadIdx.x, wv = tid >> 6, lane = tid & 63;
    int quad = lane >> 4, l15 = lane & 15;
    size_t row0 = (size_t)blockIdx.x * 64;

    // ---- LN2 ----
    for (int it = 0; it < 16; it++) {
        int t = wv*16 + it;
        const float* xp = xio + (row0 + t)*C_;
        float2 u = *(const float2*)(xp + 2*lane);
        float x0 = u.x, x1 = u.y;
        float s = x0 + x1, ss = x0*x0 + x1*x1;
        #pragma unroll
        for (int m = 32; m > 0; m >>= 1) {
            s  += __shfl_xor(s,  m, 64);
            ss += __shfl_xor(ss, m, 64);
        }
        float mean = s * (1.0f/C_);
        float var  = ss * (1.0f/C_) - mean*mean;
        float rstd = rsqrtf(var + 1e-5f);
        int c0 = 2*lane;
        ushort2 o;
        o.x = f2b((x0 - mean) * rstd * ln2_s[c0]   + ln2_b[c0]);
        o.y = f2b((x1 - mean) * rstd * ln2_s[c0+1] + ln2_b[c0+1]);
        *(ushort2*)&As[t][c0] = o;
    }

    floatx4 acc2[4][2];
    #pragma unroll
    for (int m = 0; m < 4; m++) { acc2[m][0] = fzero(); acc2[m][1] = fzero(); }

    for (int ch = 0; ch < 8; ch++) {
        __syncthreads();                      // prev chunk stage2 done
        #pragma unroll
        for (int it = 0; it < 8; it++) {      // W1 chunk: 128k x 64n
            int idx = tid + it*256;
            int k = idx >> 4, n4 = (idx & 15) * 4;
            float4 v = *(const float4*)(W1 + (size_t)k*512 + ch*64 + n4);
            ushort4 o; o.x=f2b(v.x); o.y=f2b(v.y); o.z=f2b(v.z); o.w=f2b(v.w);
            *(ushort4*)&W1c[k][n4] = o;
        }
        #pragma unroll
        for (int it = 0; it < 8; it++) {      // W2 chunk: 64k x 128n
            int idx = tid + it*256;
            int k = idx >> 5, n4 = (idx & 31) * 4;
            float4 v = *(const float4*)(W2 + (size_t)(ch*64 + k)*C_ + n4);
            ushort4 o; o.x=f2b(v.x); o.y=f2b(v.y); o.z=f2b(v.z); o.w=f2b(v.w);
            *(ushort4*)&W2c[k][n4] = o;
        }
        __syncthreads();
        // stage1: wave = n-tile; C1[64][64ch] = As @ W1c
        floatx4 a1[4];
        #pragma unroll
        for (int m = 0; m < 4; m++) a1[m] = fzero();
        #pragma unroll
        for (int kc = 0; kc < 4; kc++) {
            bf16x8 bfrag = ldfrag_strided(&W1c[kc*32 + quad*8][16*wv + l15], 68);
            #pragma unroll
            for (int m = 0; m < 4; m++) {
                bf16x8 af = ldfrag(&As[16*m + l15][kc*32 + quad*8]);
                a1[m] = MFMA16(af, bfrag, a1[m]);
            }
        }
        {   // bias + exact gelu -> G
            int c_rel = 16*wv + l15;
            float bb = b1[ch*64 + c_rel];
            #pragma unroll
            for (int m = 0; m < 4; m++)
                #pragma unroll
                for (int r = 0; r < 4; r++) {
                    int q = 16*m + 4*quad + r;
                    float hh = a1[m][r] + bb;
                    float g = 0.5f * hh * (1.0f + erff(hh * 0.70710678118654752f));
                    G[q][c_rel] = f2b(g);
                }
        }
        __syncthreads();
        // stage2: wave = n-pair; C2[64][128] += G @ W2c, K=64
        #pragma unroll
        for (int ki = 0; ki < 2; ki++) {
            bf16x8 bf0 = ldfrag_strided(&W2c[ki*32 + quad*8][32*wv + l15],      132);
            bf16x8 bf1 = ldfrag_strided(&W2c[ki*32 + quad*8][32*wv + 16 + l15], 132);
            #pragma unroll
            for (int m = 0; m < 4; m++) {
                bf16x8 af = ldfrag(&G[16*m + l15][ki*32 + quad*8]);
                acc2[m][0] = MFMA16(af, bf0, acc2[m][0]);
                acc2[m][1] = MFMA16(af, bf1, acc2[m][1]);
            }
        }
    }
    // ---- epilogue: + b2 + residual (same-thread RMW, in-place safe) ----
    {
        float bb0 = b2[32*wv + l15], bb1 = b2[32*wv + 16 + l15];
        #pragma unroll
        for (int m = 0; m < 4; m++)
            #pragma unroll
            for (int r = 0; r < 4; r++) {
                size_t rr = row0 + 16*m + 4*quad + r;
                int c0 = 32*wv + l15;
                xio[rr*C_ + c0]      += acc2[m][0][r] + bb0;
                xio[rr*C_ + c0 + 16] += acc2[m][1][r] + bb1;
            }
    }
}

extern "C" void kernel_launch(void* const* d_in, const int* in_sizes, int n_in,
                              void* d_out, int out_size, void* d_ws, size_t ws_size,
                              hipStream_t stream) {
    (void)in_sizes; (void)n_in; (void)out_size; (void)d_ws; (void)ws_size;
    const float* hidden = (const float*)d_in[0];
    const float* ln1_s  = (const float*)d_in[1];
    const float* ln1_b  = (const float*)d_in[2];
    const float* q_w    = (const float*)d_in[3];
    const float* q_b    = (const float*)d_in[4];
    const float* k_w    = (const float*)d_in[5];
    const float* k_b    = (const float*)d_in[6];
    const float* v_w    = (const float*)d_in[7];
    const float* v_b    = (const float*)d_in[8];
    const float* p_w    = (const float*)d_in[9];
    const float* p_b    = (const float*)d_in[10];
    const float* rpb    = (const float*)d_in[11];
    const float* ln2_s  = (const float*)d_in[12];
    const float* ln2_b  = (const float*)d_in[13];
    const float* fc1_w  = (const float*)d_in[14];
    const float* fc1_b  = (const float*)d_in[15];
    const float* fc2_w  = (const float*)d_in[16];
    const float* fc2_b  = (const float*)d_in[17];
    float* outp = (float*)d_out;

    swin_attn_kernel<<<B_*NW_, 256, 0, stream>>>(hidden, ln1_s, ln1_b,
            q_w, q_b, k_w, k_b, v_w, v_b, p_w, p_b, rpb, outp);
    mlp_ln_kernel<<<M_/64, 256, 0, stream>>>(outp, ln2_s, ln2_b,
            fc1_w, fc1_b, fc2_w, fc2_b);
}